// Round 1
// 128.049 us; speedup vs baseline: 1.0397x; 1.0397x over previous
//
#include <hip/hip_runtime.h>
#include <math.h>

// SinkhornM round 3:
//  - No LDS: weights read as wave-uniform loads -> s_load + SGPR operands.
//  - MLP on float2 ext-vectors -> v_pk_fma_f32 (double-rate packed FP32).
//  - EPS-free u/v Sinkhorn (EPS=1e-12 vs sums >= ~2e-3: rel err ~5e-10/iter).
//  - tau matrix entirely in exp2/log2 space: geometric means = exp2 of
//    averaged l-values, no sqrtf fixup sequences.

#define QLOW  0.02f
#define QSPAN 0.96f
#define L2E   1.44269504088896f

constexpr int R = 2;

typedef __attribute__((ext_vector_type(2))) float f32x2;

__device__ __forceinline__ float frcp(float x) { return __builtin_amdgcn_rcpf(x); }
__device__ __forceinline__ f32x2 pfma(f32x2 a, f32x2 b, f32x2 c) {
    return __builtin_elementwise_fma(a, b, c);
}

__global__ __launch_bounds__(256) void sinkhorn_fused(
    const float* __restrict__ margins,
    const float* __restrict__ W1, const float* __restrict__ b1,
    const float* __restrict__ W2, const float* __restrict__ b2,
    const float* __restrict__ W3, const float* __restrict__ b3,
    float* __restrict__ out, int n)
{
    const int tid  = blockIdx.x * blockDim.x + threadIdx.x;
    const int lane = tid & 63;
    const int base = (tid >> 6) * (64 * R) + lane;  // rows base, base+64

    const float4* __restrict__ m4 = (const float4*)margins;

    float m[R][8];
#pragma unroll
    for (int r = 0; r < R; ++r) {
        const int row = base + 64 * r;
        const float4 a0 = m4[row * 2 + 0];
        const float4 a1 = m4[row * 2 + 1];
        m[r][0] = a0.x; m[r][1] = a0.y; m[r][2] = a0.z; m[r][3] = a0.w;
        m[r][4] = a1.x; m[r][5] = a1.y; m[r][6] = a1.z; m[r][7] = a1.w;
    }

    const f32x2* __restrict__ W1v = (const f32x2*)W1;  // (8,32) -> [k][16 pairs]
    const f32x2* __restrict__ W2v = (const f32x2*)W2;  // (32,16) -> [k][8 pairs]
    const f32x2* __restrict__ b1v = (const f32x2*)b1;
    const f32x2* __restrict__ b2v = (const f32x2*)b2;

    // ---- layer 1: h1 = relu(m @ W1 + b1), 32 wide = 16 pairs ----
    f32x2 h1[R][16];
#pragma unroll
    for (int j = 0; j < 16; ++j) {
        const f32x2 bb = b1v[j];
#pragma unroll
        for (int r = 0; r < R; ++r) h1[r][j] = bb;
    }
#pragma unroll
    for (int k = 0; k < 8; ++k) {
        f32x2 mk[R];
#pragma unroll
        for (int r = 0; r < R; ++r) { mk[r].x = m[r][k]; mk[r].y = m[r][k]; }
#pragma unroll
        for (int j = 0; j < 16; ++j) {
            const f32x2 w = W1v[k * 16 + j];
#pragma unroll
            for (int r = 0; r < R; ++r) h1[r][j] = pfma(mk[r], w, h1[r][j]);
        }
    }
    const f32x2 zero2 = {0.0f, 0.0f};
#pragma unroll
    for (int j = 0; j < 16; ++j)
#pragma unroll
        for (int r = 0; r < R; ++r)
            h1[r][j] = __builtin_elementwise_max(h1[r][j], zero2);

    // ---- layer 2: h2 = relu(h1 @ W2 + b2), 16 wide = 8 pairs ----
    f32x2 h2[R][8];
#pragma unroll
    for (int j = 0; j < 8; ++j) {
        const f32x2 bb = b2v[j];
#pragma unroll
        for (int r = 0; r < R; ++r) h2[r][j] = bb;
    }
#pragma unroll
    for (int k = 0; k < 32; ++k) {
        f32x2 hk[R];
#pragma unroll
        for (int r = 0; r < R; ++r) {
            const float s = (k & 1) ? h1[r][k >> 1].y : h1[r][k >> 1].x;
            hk[r].x = s; hk[r].y = s;
        }
#pragma unroll
        for (int j = 0; j < 8; ++j) {
            const f32x2 w = W2v[k * 8 + j];
#pragma unroll
            for (int r = 0; r < R; ++r) h2[r][j] = pfma(hk[r], w, h2[r][j]);
        }
    }
#pragma unroll
    for (int j = 0; j < 8; ++j)
#pragma unroll
        for (int r = 0; r < R; ++r)
            h2[r][j] = __builtin_elementwise_max(h2[r][j], zero2);

    // ---- layer 3: p = h2 @ W3 + b3, 9 wide = 4 pairs + 1 scalar ----
    f32x2 p01[R], p23[R], p45[R], p67[R];
    float p8[R];
    {
        const f32x2 b01 = {b3[0], b3[1]};
        const f32x2 b23 = {b3[2], b3[3]};
        const f32x2 b45 = {b3[4], b3[5]};
        const f32x2 b67 = {b3[6], b3[7]};
        const float b8  = b3[8];
#pragma unroll
        for (int r = 0; r < R; ++r) {
            p01[r] = b01; p23[r] = b23; p45[r] = b45; p67[r] = b67; p8[r] = b8;
        }
    }
#pragma unroll
    for (int k = 0; k < 16; ++k) {
        const f32x2 w01 = {W3[k * 9 + 0], W3[k * 9 + 1]};
        const f32x2 w23 = {W3[k * 9 + 2], W3[k * 9 + 3]};
        const f32x2 w45 = {W3[k * 9 + 4], W3[k * 9 + 5]};
        const f32x2 w67 = {W3[k * 9 + 6], W3[k * 9 + 7]};
        const float w8  = W3[k * 9 + 8];
#pragma unroll
        for (int r = 0; r < R; ++r) {
            const float s = (k & 1) ? h2[r][k >> 1].y : h2[r][k >> 1].x;
            f32x2 hb; hb.x = s; hb.y = s;
            p01[r] = pfma(hb, w01, p01[r]);
            p23[r] = pfma(hb, w23, p23[r]);
            p45[r] = pfma(hb, w45, p45[r]);
            p67[r] = pfma(hb, w67, p67[r]);
            p8[r]  = fmaf(s, w8, p8[r]);
        }
    }

    float4* __restrict__ o4 = (float4*)out;
    float* __restrict__ oV = out + (size_t)n * 16;

#pragma unroll
    for (int r = 0; r < R; ++r) {
        const int row = base + 64 * r;

        const float l0 = p01[r].x * L2E, l1 = p01[r].y * L2E;
        const float l2 = p23[r].x * L2E, l3 = p23[r].y * L2E;

        const float a00 = exp2f(l0), a01 = exp2f(l1);
        const float a10 = exp2f(l2), a11 = exp2f(l3);
        const float h01 = (l0 + l1) * 0.5f, h23 = (l2 + l3) * 0.5f;
        const float a02 = exp2f(h01);
        const float a12 = exp2f(h23);
        const float a20 = exp2f((l0 + l2) * 0.5f);
        const float a21 = exp2f((l1 + l3) * 0.5f);
        const float a22 = exp2f((h01 + h23) * 0.5f);

        const float s4 = fmaf(QSPAN, frcp(1.0f + exp2f(-L2E * p45[r].x)), QLOW);
        const float s5 = fmaf(QSPAN, frcp(1.0f + exp2f(-L2E * p45[r].y)), QLOW);
        const float s6 = fmaf(QSPAN, frcp(1.0f + exp2f(-L2E * p67[r].x)), QLOW);
        const float s7 = fmaf(QSPAN, frcp(1.0f + exp2f(-L2E * p67[r].y)), QLOW);

        const float M0 = m[r][0], M1 = m[r][1], M2 = m[r][2];
        const float F0 = m[r][3], F1 = m[r][4], F2 = m[r][5];

        const float rm0 = M0 * s4, rm1 = M1 * s5, rm2 = M2;
        const float cm0 = F0 * s6, cm1 = F1 * s7, cm2 = F2;
        const float um0 = fmaf(-s4, M0, M0);
        const float um1 = fmaf(-s5, M1, M1);
        const float uf0 = fmaf(-s6, F0, F0);
        const float uf1 = fmaf(-s7, F1, F1);

        float v0 = 1.0f, v1 = 1.0f, v2 = 1.0f;
        float u0 = 1.0f, u1 = 1.0f, u2 = 1.0f;
#pragma unroll
        for (int it = 0; it < 10; ++it) {
            // row normalize: u_i = rm_i / sum_j a_ij v_j   (EPS dropped)
            const float t0 = fmaf(a02, v2, fmaf(a01, v1, a00 * v0));
            const float t1 = fmaf(a12, v2, fmaf(a11, v1, a10 * v0));
            const float t2 = fmaf(a22, v2, fmaf(a21, v1, a20 * v0));
            u0 = rm0 * frcp(t0);
            u1 = rm1 * frcp(t1);
            u2 = rm2 * frcp(t2);
            // col normalize: v_j = cm_j / sum_i a_ij u_i
            const float q0 = fmaf(a20, u2, fmaf(a10, u1, a00 * u0));
            const float q1 = fmaf(a21, u2, fmaf(a11, u1, a01 * u0));
            const float q2 = fmaf(a22, u2, fmaf(a12, u1, a02 * u0));
            v0 = cm0 * frcp(q0);
            v1 = cm1 * frcp(q1);
            v2 = cm2 * frcp(q2);
        }

        o4[row * 4 + 0] = make_float4(u0 * a00 * v0, u0 * a01 * v1, u0 * a02 * v2, um0);
        o4[row * 4 + 1] = make_float4(u1 * a10 * v0, u1 * a11 * v1, u1 * a12 * v2, um1);
        o4[row * 4 + 2] = make_float4(u2 * a20 * v0, u2 * a21 * v1, u2 * a22 * v2, 0.0f);
        o4[row * 4 + 3] = make_float4(uf0, uf1, 0.0f, 0.0f);
        oV[row] = exp2f(p8[r] * L2E);
    }
}

extern "C" void kernel_launch(void* const* d_in, const int* in_sizes, int n_in,
                              void* d_out, int out_size, void* d_ws, size_t ws_size,
                              hipStream_t stream) {
    const float* margins = (const float*)d_in[0];
    const float* W1 = (const float*)d_in[1];
    const float* b1 = (const float*)d_in[2];
    const float* W2 = (const float*)d_in[3];
    const float* b2 = (const float*)d_in[4];
    const float* W3 = (const float*)d_in[5];
    const float* b3 = (const float*)d_in[6];

    const int n = in_sizes[0] / 8;       // 1,048,576 rows
    const int threads = n / R;
    dim3 block(256), grid(threads / 256);

    sinkhorn_fused<<<grid, block, 0, stream>>>(margins, W1, b1, W2, b2, W3, b3,
                                               (float*)d_out, n);
}